// Round 13
// baseline (168.147 us; speedup 1.0000x reference)
//
#include <hip/hip_runtime.h>
#include <stdint.h>

// Problem constants (B=2048, N=16, T=1024)
#define T_STEPS 1024
#define NWORDS  256          // u64 mask words per batch (4 timesteps per word)
#define NB      8            // batches per scan block
#define SCAN_BLOCK (NB * 16) // 128 threads: 8 batches x 16 output neurons
#define NSEG    4            // time segments (64 output words each)

typedef float f32x4 __attribute__((ext_vector_type(4)));

// ---------------------------------------------------------------------------
// Kernel 1 (R9-proven): blocks 0..B-1: spikes -> 16-bit masks (HBM-bound
// 128 MiB read, ~21 us). Block B: build the 64 KiB f64 byte table in global
// memory, concurrent with the mask blocks. All w[] indices compile-time.
// tab[s*4096 + byte*16 + o] = (lo-nibble ordered sum)+(hi-nibble ordered sum)
// == z_{2s} + z_{2s+1} with the EXACT association tree of the absmax-0 rounds.
// ---------------------------------------------------------------------------
__global__ __launch_bounds__(256) void k_maskify(const float* __restrict__ spike,
                                                 unsigned long long* __restrict__ masks,
                                                 const float* __restrict__ W,
                                                 double* __restrict__ tab,
                                                 int B) {
    const int b  = blockIdx.x;
    const int tc = threadIdx.x;
    if (b < B) {
        const float4* sp = reinterpret_cast<const float4*>(spike) + (size_t)b * (16 * NWORDS);
        unsigned int m0 = 0, m1 = 0, m2 = 0, m3 = 0;
#pragma unroll
        for (int i = 0; i < 16; ++i) {
            float4 v = sp[i * NWORDS + tc];
            m0 |= (v.x >= 0.5f) ? (1u << i) : 0u;
            m1 |= (v.y >= 0.5f) ? (1u << i) : 0u;
            m2 |= (v.z >= 0.5f) ? (1u << i) : 0u;
            m3 |= (v.w >= 0.5f) ? (1u << i) : 0u;
        }
        masks[(size_t)b * NWORDS + tc] =
            (unsigned long long)m0 | ((unsigned long long)m1 << 16) |
            ((unsigned long long)m2 << 32) | ((unsigned long long)m3 << 48);
    } else {
        const int o = tc & 15;
        double w[16];
#pragma unroll
        for (int j = 0; j < 16; ++j) w[j] = (double)W[o * 16 + j];
#pragma unroll
        for (int k = 0; k < 32; ++k) {                 // fully unrolled
            const int e    = tc + k * 256;
            const int byte = (e >> 4) & 255;
            const int s    = k >> 4;                   // COMPILE-TIME constant
            double slo = 0.0, shi = 0.0;
#pragma unroll
            for (int j = 0; j < 4; ++j) slo += (byte & (1 << j))  ? w[8 * s + j]     : 0.0;
#pragma unroll
            for (int j = 0; j < 4; ++j) shi += (byte & (16 << j)) ? w[8 * s + 4 + j] : 0.0;
            tab[s * 4096 + byte * 16 + o] = slo + shi; // = z_{2s} + z_{2s+1}
        }
    }
}

// ---------------------------------------------------------------------------
// Kernel 2: CUBA LIF scan — R11's asm pipeline (proven absmax 0.0),
// EXACT-prefix time segments for occupancy (no warm-up approximation):
//   seg k: computes words [0, 64k+64) from the TRUE zero state at t=0
//          (bit-identical truncated replay of the R11 stream), writes only
//          words [64k, 64k+64) to `out`; earlier words go to a dump region
//          (concurrent duplicate writes there carry identical values and
//          are never read).
// Grid = 1024 blocks = 2048 waves = 2 waves/SIMD: co-resident waves fill
// each other's stall slots (R11: 665 cyc/word vs ~200 issue at 1 wave/SIMD).
// Body(w): GLM mask(w+6); s_waitcnt vmcnt(20); COMPUTE word w; TISSUE w+4.
// ---------------------------------------------------------------------------
__global__ __launch_bounds__(SCAN_BLOCK, 2) void k_scan(const double* __restrict__ tab,
                                                        const unsigned long long* __restrict__ masks,
                                                        float* __restrict__ out,
                                                        float* __restrict__ dump) {
    const int tid = threadIdx.x;
    const int bb  = tid >> 4;
    const int o   = tid & 15;
    const int seg = blockIdx.x & (NSEG - 1);
    const int blk = blockIdx.x >> 2;
    const int b   = blk * NB + bb;

    const int nw    = 64 * seg + 64;   // words computed (exact prefix)
    const int wout0 = 64 * seg;        // first word written to `out`

    const uint64_t tb     = (uint64_t)tab;
    const uint64_t mb     = (uint64_t)masks;
    const uint64_t ob_out = (uint64_t)out;
    const uint64_t db_out = (uint64_t)dump;
    const uint32_t ob0    = (uint32_t)(o * 8);
    const uint32_t ob1    = ob0 + 32768u;
    const uint32_t vb_m   = (uint32_t)(b * (NWORDS * 8));
    const uint32_t vb_out = (uint32_t)(b * (T_STEPS * 4));
    const int grp_sh      = tid & 48;
    const bool writer     = (o == 0);

    double c = 0.0, v = 0.0;

    // Four rotating table sets (word w lives in set w mod 4) + 6 mask regs.
    double T0_0, T0_1, T0_2, T0_3, T0_4, T0_5, T0_6, T0_7;
    double T1_0, T1_1, T1_2, T1_3, T1_4, T1_5, T1_6, T1_7;
    double T2_0, T2_1, T2_2, T2_3, T2_4, T2_5, T2_6, T2_7;
    double T3_0, T3_1, T3_2, T3_3, T3_4, T3_5, T3_6, T3_7;
    unsigned long long MA, MB, MC, MD, q0, q1;

#define GLT(DST, VOFF) \
    asm volatile("global_load_dwordx2 %0, %1, %2" : "=v"(DST) : "v"(VOFF), "s"(tb) : "memory")
#define GLM(DST, IDX) do { int _mi = (IDX); if (_mi > 255) _mi = 255;                 \
    const uint32_t _vo = vb_m + ((uint32_t)_mi << 3);                                 \
    asm volatile("global_load_dwordx2 %0, %1, %2" : "=v"(DST) : "v"(_vo), "s"(mb) : "memory"); } while (0)
#define WAITV(N) asm volatile("s_waitcnt vmcnt(" #N ")" ::: "memory")
#define SBAR __builtin_amdgcn_sched_barrier(0)

#define TISSUE(P, MW) do {                                                            \
    const uint32_t _lo = (uint32_t)(MW), _hi = (uint32_t)((MW) >> 32);                \
    uint32_t _a;                                                                      \
    _a = ob0 + ((_lo & 255u) << 7);          GLT(P##_0, _a);                          \
    _a = ob1 + (((_lo >> 8) & 255u) << 7);   GLT(P##_1, _a);                          \
    _a = ob0 + (((_lo >> 16) & 255u) << 7);  GLT(P##_2, _a);                          \
    _a = ob1 + ((_lo >> 24) << 7);           GLT(P##_3, _a);                          \
    _a = ob0 + ((_hi & 255u) << 7);          GLT(P##_4, _a);                          \
    _a = ob1 + (((_hi >> 8) & 255u) << 7);   GLT(P##_5, _a);                          \
    _a = ob0 + (((_hi >> 16) & 255u) << 7);  GLT(P##_6, _a);                          \
    _a = ob1 + ((_hi >> 24) << 7);           GLT(P##_7, _a);                          \
} while (0)

    // One recurrence step; numerics identical to the absmax-0 rounds.
#define ZSTEP(ZL, ZH, OWEL) do {                                                      \
    const double _z = (ZL) + (ZH);                                                    \
    c = fma(c, 0.75, _z);                                                             \
    v = fma(v, 0.97, c);                                                              \
    const bool _s = (v >= 1.25);                                                      \
    const unsigned long long _bal = __ballot(_s);                                     \
    v = _s ? 0.0 : v;                                                                 \
    const uint32_t _k = __popc((uint32_t)(_bal >> grp_sh) & 0xFFFFu);                 \
    OWEL = exp2f(fmaf((float)_k, 0.62581400f, 16.0f));                                \
} while (0)

    // Store ALWAYS issued (ledger constant); base selects out vs dump.
    // (wd >= wout0) is wave-uniform -> scalar base select.
#define COMPUTE(P, WD) do {                                                           \
    f32x4 _ow;                                                                        \
    ZSTEP(P##_0, P##_1, _ow.x);                                                       \
    ZSTEP(P##_2, P##_3, _ow.y);                                                       \
    ZSTEP(P##_4, P##_5, _ow.z);                                                       \
    ZSTEP(P##_6, P##_7, _ow.w);                                                       \
    if (writer) {                                                                     \
        const uint64_t _sb = ((WD) >= wout0) ? ob_out : db_out;                       \
        const uint32_t _vo = vb_out + ((uint32_t)(WD) << 4);                          \
        asm volatile("global_store_dwordx4 %0, %1, %2"                                \
                     :: "v"(_vo), "v"(_ow), "s"(_sb) : "memory");                     \
    }                                                                                 \
} while (0)

#define BODY(WD, P, MU, MI) do {                                                      \
    GLM(MI, (WD) + 6);                                                                \
    WAITV(20); SBAR;                                                                  \
    COMPUTE(P, WD);                                                                   \
    TISSUE(P, MU); SBAR;                                                              \
} while (0)

    asm volatile("s_waitcnt vmcnt(0) lgkmcnt(0)" ::: "memory");

    // Prologue: 6 masks in flight; tables for words 0..3 issued.
    GLM(q0, 0); GLM(q1, 1); GLM(MA, 2); GLM(MB, 3); GLM(MC, 4); GLM(MD, 5);
    WAITV(2); SBAR;                 // m0..m3 ready; MC,MD outstanding
    TISSUE(T0, q0);
    TISSUE(T1, q1);
    TISSUE(T2, MA);
    TISSUE(T3, MB); SBAR;           // outstanding: 2 masks + 32 table loads

    // Main loop: nw-4 bodies, period-4 register rotation ((nw-4) % 4 == 0).
    for (int w = 0; w < nw - 4; w += 4) {
        BODY(w,     T0, MC, MA);
        BODY(w + 1, T1, MD, MB);
        BODY(w + 2, T2, MA, MC);
        BODY(w + 3, T3, MB, MD);
    }

    // Epilogue: last 4 words (T(e0) already forced at the final body).
    const int e0 = nw - 4;
    COMPUTE(T0, e0);
    WAITV(21); SBAR;
    COMPUTE(T1, e0 + 1);
    WAITV(12); SBAR;
    COMPUTE(T2, e0 + 2);
    WAITV(3); SBAR;
    COMPUTE(T3, e0 + 3);
    asm volatile("s_waitcnt vmcnt(0)" ::: "memory");  // drain stores

#undef GLT
#undef GLM
#undef WAITV
#undef SBAR
#undef TISSUE
#undef ZSTEP
#undef COMPUTE
#undef BODY
}

// ---------------------------------------------------------------------------
// Fallback (only if d_ws too small — never observed): R1-style scan.
// ---------------------------------------------------------------------------
__global__ __launch_bounds__(SCAN_BLOCK) void k_scan_fb(const float* __restrict__ W,
                                                        const float* __restrict__ spike,
                                                        float* __restrict__ out) {
    __shared__ double ztab[4][16][16];
    __shared__ unsigned long long mlds[NB][NWORDS];
    __shared__ float outtab[17];
    const int tid = threadIdx.x, bb = tid >> 4, o = tid & 15;
    for (int e = tid; e < 4 * 16 * 16; e += SCAN_BLOCK) {
        const int oo = e & 15, idx = (e >> 4) & 15, seg = e >> 8;
        double s = 0.0;
#pragma unroll
        for (int j = 0; j < 4; ++j)
            if (idx & (1 << j)) s += (double)W[oo * 16 + seg * 4 + j];
        ztab[seg][idx][oo] = s;
    }
    if (tid < 17) {
        const double ln2 = 0.69314718055994530941723212145818;
        const double l2c1 = log(2.0 * cosh(1.0));
        outtab[tid] = (float)exp((16.0 - (double)tid) * ln2 + (double)tid * l2c1);
    }
    {
        const int part = tid & 15;
        const float4* spb = reinterpret_cast<const float4*>(spike) +
                            (size_t)(blockIdx.x * NB + bb) * (16 * NWORDS);
        for (int w = 0; w < 16; ++w) {
            const int tc = part * 16 + w;
            unsigned int m0 = 0, m1 = 0, m2 = 0, m3 = 0;
#pragma unroll
            for (int i = 0; i < 16; ++i) {
                float4 v = spb[i * NWORDS + tc];
                m0 |= (v.x >= 0.5f) ? (1u << i) : 0u;
                m1 |= (v.y >= 0.5f) ? (1u << i) : 0u;
                m2 |= (v.z >= 0.5f) ? (1u << i) : 0u;
                m3 |= (v.w >= 0.5f) ? (1u << i) : 0u;
            }
            mlds[bb][tc] = (unsigned long long)m0 | ((unsigned long long)m1 << 16) |
                           ((unsigned long long)m2 << 32) | ((unsigned long long)m3 << 48);
        }
    }
    __syncthreads();
    double c = 0.0, v = 0.0;
    const int b = blockIdx.x * NB + bb;
    float* outp = out + (size_t)b * T_STEPS;
    const int grp_sh = tid & 48;
    const bool writer = (o == 0);
    for (int tg = 0; tg < NWORDS; ++tg) {
        const unsigned long long mw = mlds[bb][tg];
#pragma unroll
        for (int j = 0; j < 4; ++j) {
            const unsigned int m = (unsigned int)(mw >> (16 * j)) & 0xFFFFu;
            const double z = (ztab[0][m & 15][o] + ztab[1][(m >> 4) & 15][o]) +
                             (ztab[2][(m >> 8) & 15][o] + ztab[3][(m >> 12) & 15][o]);
            c = fma(c, 0.75, z);
            v = fma(v, 0.97, c);
            const bool s = (v >= 1.25);
            const unsigned long long bal = __ballot(s);
            v = s ? 0.0 : v;
            if (writer) outp[tg * 4 + j] = outtab[(int)__popcll((bal >> grp_sh) & 0xFFFFull)];
        }
    }
}

extern "C" void kernel_launch(void* const* d_in, const int* in_sizes, int n_in,
                              void* d_out, int out_size, void* d_ws, size_t ws_size,
                              hipStream_t stream) {
    const float* spike = (const float*)d_in[0];
    const float* W     = (const float*)d_in[1];
    float* out         = (float*)d_out;

    const int B = in_sizes[0] / (16 * T_STEPS);  // 2048

    const size_t mask_bytes = (size_t)B * NWORDS * sizeof(unsigned long long);  // 4 MiB
    const size_t tab_bytes  = 2 * 256 * 16 * sizeof(double);                    // 64 KiB
    const size_t dump_bytes = (size_t)B * T_STEPS * sizeof(float);              // 8 MiB

    if (ws_size >= mask_bytes + tab_bytes + dump_bytes) {
        unsigned long long* masks = (unsigned long long*)d_ws;
        double* tab = (double*)((char*)d_ws + mask_bytes);
        float* dump = (float*)((char*)d_ws + mask_bytes + tab_bytes);
        // Grid B+1: blocks 0..B-1 build masks, block B builds the byte table.
        k_maskify<<<B + 1, 256, 0, stream>>>(spike, masks, W, tab, B);
        // 4 exact-prefix time segments x 256 batch-blocks = 2 waves/SIMD.
        k_scan<<<(B / NB) * NSEG, SCAN_BLOCK, 0, stream>>>(tab, masks, out, dump);
    } else {
        k_scan_fb<<<B / NB, SCAN_BLOCK, 0, stream>>>(W, spike, out);
    }
}

// Round 14
// 90.813 us; speedup vs baseline: 1.8516x; 1.8516x over previous
//
#include <hip/hip_runtime.h>
#include <stdint.h>

// Problem constants (B=2048, N=16, T=1024)
#define T_STEPS 1024
#define NWORDS  256          // u64 mask words per batch (4 timesteps per word)
#define NB      8            // batches per scan block
#define SCAN_BLOCK (NB * 16) // 128 threads: 8 batches x 16 output neurons

typedef float f32x4 __attribute__((ext_vector_type(4)));

// ---------------------------------------------------------------------------
// Kernel 1 (R9-proven): blocks 0..B-1: spikes -> 16-bit masks (HBM-bound
// 128 MiB read, ~21 us). Block B: build the 64 KiB f64 byte table in global
// memory, concurrent with the mask blocks. All w[] indices compile-time.
// tab[s*4096 + byte*16 + o] = (lo-nibble ordered sum)+(hi-nibble ordered sum)
// == z_{2s} + z_{2s+1} with the EXACT association tree of the absmax-0 rounds.
// ---------------------------------------------------------------------------
__global__ __launch_bounds__(256) void k_maskify(const float* __restrict__ spike,
                                                 unsigned long long* __restrict__ masks,
                                                 const float* __restrict__ W,
                                                 double* __restrict__ tab,
                                                 int B) {
    const int b  = blockIdx.x;
    const int tc = threadIdx.x;
    if (b < B) {
        const float4* sp = reinterpret_cast<const float4*>(spike) + (size_t)b * (16 * NWORDS);
        unsigned int m0 = 0, m1 = 0, m2 = 0, m3 = 0;
#pragma unroll
        for (int i = 0; i < 16; ++i) {
            float4 v = sp[i * NWORDS + tc];
            m0 |= (v.x >= 0.5f) ? (1u << i) : 0u;
            m1 |= (v.y >= 0.5f) ? (1u << i) : 0u;
            m2 |= (v.z >= 0.5f) ? (1u << i) : 0u;
            m3 |= (v.w >= 0.5f) ? (1u << i) : 0u;
        }
        masks[(size_t)b * NWORDS + tc] =
            (unsigned long long)m0 | ((unsigned long long)m1 << 16) |
            ((unsigned long long)m2 << 32) | ((unsigned long long)m3 << 48);
    } else {
        const int o = tc & 15;
        double w[16];
#pragma unroll
        for (int j = 0; j < 16; ++j) w[j] = (double)W[o * 16 + j];
#pragma unroll
        for (int k = 0; k < 32; ++k) {                 // fully unrolled
            const int e    = tc + k * 256;
            const int byte = (e >> 4) & 255;
            const int s    = k >> 4;                   // COMPILE-TIME constant
            double slo = 0.0, shi = 0.0;
#pragma unroll
            for (int j = 0; j < 4; ++j) slo += (byte & (1 << j))  ? w[8 * s + j]     : 0.0;
#pragma unroll
            for (int j = 0; j < 4; ++j) shi += (byte & (16 << j)) ? w[8 * s + 4 + j] : 0.0;
            tab[s * 4096 + byte * 16 + o] = slo + shi; // = z_{2s} + z_{2s+1}
        }
    }
}

// ---------------------------------------------------------------------------
// Kernel 2: CUBA LIF scan — asm-pipelined, all-vmcnt, DEPTH-2 with only TWO
// table register sets (16 doubles = 32 VGPRs live; R13's profile proved the
// 4-set version spilled to scratch: VGPR_Count=44 < 64 live doubles, which
// serialized every load behind a compiler spill-store since R8).
// Word w uses set (w&1): even->TA, odd->TB. Body w issues T(w+2) into the
// set just freed by COMPUTE(w).
// vmcnt ledger (hand-verified): steady entry = 20 outstanding
//   [m(w+2), S(w-2), T(w)x8, m(w+3), S(w-1), T(w+1)x8];
// body: GLM m(w+4) -> 21; WAITV(11) forces m(w+2)+S(w-2)+T(w)x8;
// COMPUTE(w) -> +store; TISSUE(w+2) -> back to 20.
// Prologue peels body 0 (WAITV(9)) and body 1 (WAITV(11)); epilogue 10/1/0.
// Loads have NO "memory" clobber (volatile order + SBAR after each wait pin
// the schedule); stores/waits keep it. Numerics identical to absmax-0 rounds.
// ---------------------------------------------------------------------------
__global__ __launch_bounds__(SCAN_BLOCK, 1) void k_scan(const double* __restrict__ tab,
                                                        const unsigned long long* __restrict__ masks,
                                                        float* __restrict__ out) {
    const int tid = threadIdx.x;
    const int bb  = tid >> 4;
    const int o   = tid & 15;
    const int b   = blockIdx.x * NB + bb;

    const uint64_t tb     = (uint64_t)tab;
    const uint64_t mb     = (uint64_t)masks;
    const uint64_t ob_out = (uint64_t)out;
    const uint32_t ob0    = (uint32_t)(o * 8);
    const uint32_t ob1    = ob0 + 32768u;
    const uint32_t vb_m   = (uint32_t)(b * (NWORDS * 8));
    const uint32_t vb_out = (uint32_t)(b * (T_STEPS * 4));
    const int grp_sh      = tid & 48;
    const bool writer     = (o == 0);

    double c = 0.0, v = 0.0;

    // TWO rotating table sets + 4 rotating mask regs + 2 prologue masks.
    double TA_0, TA_1, TA_2, TA_3, TA_4, TA_5, TA_6, TA_7;
    double TB_0, TB_1, TB_2, TB_3, TB_4, TB_5, TB_6, TB_7;
    unsigned long long MA, MB, MC, MD, q0, q1;

#define GLT(DST, VOFF) \
    asm volatile("global_load_dwordx2 %0, %1, %2" : "=v"(DST) : "v"(VOFF), "s"(tb))
#define GLM(DST, IDX) do { int _mi = (IDX); if (_mi > 255) _mi = 255;                 \
    const uint32_t _vo = vb_m + ((uint32_t)_mi << 3);                                 \
    asm volatile("global_load_dwordx2 %0, %1, %2" : "=v"(DST) : "v"(_vo), "s"(mb)); } while (0)
#define WAITV(N) asm volatile("s_waitcnt vmcnt(" #N ")" ::: "memory")
#define SBAR __builtin_amdgcn_sched_barrier(0)

#define TISSUE(P, MW) do {                                                            \
    const uint32_t _lo = (uint32_t)(MW), _hi = (uint32_t)((MW) >> 32);                \
    uint32_t _a;                                                                      \
    _a = ob0 + ((_lo & 255u) << 7);          GLT(P##_0, _a);                          \
    _a = ob1 + (((_lo >> 8) & 255u) << 7);   GLT(P##_1, _a);                          \
    _a = ob0 + (((_lo >> 16) & 255u) << 7);  GLT(P##_2, _a);                          \
    _a = ob1 + ((_lo >> 24) << 7);           GLT(P##_3, _a);                          \
    _a = ob0 + ((_hi & 255u) << 7);          GLT(P##_4, _a);                          \
    _a = ob1 + (((_hi >> 8) & 255u) << 7);   GLT(P##_5, _a);                          \
    _a = ob0 + (((_hi >> 16) & 255u) << 7);  GLT(P##_6, _a);                          \
    _a = ob1 + ((_hi >> 24) << 7);           GLT(P##_7, _a);                          \
} while (0)

    // One recurrence step; numerics identical to the absmax-0 rounds:
    // z = (z01)+(z23) via table halves, fma(c,0.75,z), fma(v,0.97,c).
#define ZSTEP(ZL, ZH, OWEL) do {                                                      \
    const double _z = (ZL) + (ZH);                                                    \
    c = fma(c, 0.75, _z);                                                             \
    v = fma(v, 0.97, c);                                                              \
    const bool _s = (v >= 1.25);                                                      \
    const unsigned long long _bal = __ballot(_s);                                     \
    v = _s ? 0.0 : v;                                                                 \
    const uint32_t _k = __popc((uint32_t)(_bal >> grp_sh) & 0xFFFFu);                 \
    OWEL = exp2f(fmaf((float)_k, 0.62581400f, 16.0f));                                \
} while (0)

#define COMPUTE(P, WD) do {                                                           \
    f32x4 _ow;                                                                        \
    ZSTEP(P##_0, P##_1, _ow.x);                                                       \
    ZSTEP(P##_2, P##_3, _ow.y);                                                       \
    ZSTEP(P##_4, P##_5, _ow.z);                                                       \
    ZSTEP(P##_6, P##_7, _ow.w);                                                       \
    if (writer) {                                                                     \
        const uint32_t _vo = vb_out + ((uint32_t)(WD) << 4);                          \
        asm volatile("global_store_dwordx4 %0, %1, %2"                                \
                     :: "v"(_vo), "v"(_ow), "s"(ob_out) : "memory");                  \
    }                                                                                 \
} while (0)

#define BODY(WD, P, MU, MI) do {                                                      \
    GLM(MI, (WD) + 4);                                                                \
    WAITV(11); SBAR;                                                                  \
    COMPUTE(P, WD);                                                                   \
    TISSUE(P, MU); SBAR;                                                              \
} while (0)

    asm volatile("s_waitcnt vmcnt(0) lgkmcnt(0)" ::: "memory");

    // Prologue: masks 0..3 in flight; tables for words 0,1 issued.
    GLM(q0, 0); GLM(q1, 1); GLM(MA, 2); GLM(MB, 3);
    WAITV(2); SBAR;                 // m0,m1 ready; [MA,MB] outstanding
    TISSUE(TA, q0);
    TISSUE(TB, q1); SBAR;           // outstanding: MA,MB,TA8,TB8 = 18

    // Peeled body 0: GLM m4 -> 19; force MA,MB,TA8 (10) -> WAITV(9).
    GLM(MC, 4);
    WAITV(9); SBAR;
    COMPUTE(TA, 0);                 // +S0 -> 10
    TISSUE(TA, MA); SBAR;           // T(2) -> 18

    // Peeled body 1: GLM m5 -> 19; force TB8 (8 oldest) -> WAITV(11).
    GLM(MD, 5);
    WAITV(11); SBAR;
    COMPUTE(TB, 1);                 // +S1 -> 12
    TISSUE(TB, MB); SBAR;           // T(3) -> 20  == steady invariant

    // Steady: words 2..253, unrolled x4 (mask rotation period).
    for (int w = 2; w < 254; w += 4) {
        BODY(w,     TA, MC, MA);    // uses m(w+2)=MC, loads m(w+4)->MA
        BODY(w + 1, TB, MD, MB);
        BODY(w + 2, TA, MA, MC);
        BODY(w + 3, TB, MB, MD);
    }

    // Epilogue: word 254 in TA, word 255 in TB.
    WAITV(10); SBAR;                // force TA(254)x8 (+2 older)
    COMPUTE(TA, 254);
    WAITV(1); SBAR;                 // force TB(255)x8 (+2 older), leave S254
    COMPUTE(TB, 255);
    asm volatile("s_waitcnt vmcnt(0)" ::: "memory");  // drain stores

#undef GLT
#undef GLM
#undef WAITV
#undef SBAR
#undef TISSUE
#undef ZSTEP
#undef COMPUTE
#undef BODY
}

// ---------------------------------------------------------------------------
// Fallback (only if d_ws too small — never observed): R1-style scan.
// ---------------------------------------------------------------------------
__global__ __launch_bounds__(SCAN_BLOCK) void k_scan_fb(const float* __restrict__ W,
                                                        const float* __restrict__ spike,
                                                        float* __restrict__ out) {
    __shared__ double ztab[4][16][16];
    __shared__ unsigned long long mlds[NB][NWORDS];
    __shared__ float outtab[17];
    const int tid = threadIdx.x, bb = tid >> 4, o = tid & 15;
    for (int e = tid; e < 4 * 16 * 16; e += SCAN_BLOCK) {
        const int oo = e & 15, idx = (e >> 4) & 15, seg = e >> 8;
        double s = 0.0;
#pragma unroll
        for (int j = 0; j < 4; ++j)
            if (idx & (1 << j)) s += (double)W[oo * 16 + seg * 4 + j];
        ztab[seg][idx][oo] = s;
    }
    if (tid < 17) {
        const double ln2 = 0.69314718055994530941723212145818;
        const double l2c1 = log(2.0 * cosh(1.0));
        outtab[tid] = (float)exp((16.0 - (double)tid) * ln2 + (double)tid * l2c1);
    }
    {
        const int part = tid & 15;
        const float4* spb = reinterpret_cast<const float4*>(spike) +
                            (size_t)(blockIdx.x * NB + bb) * (16 * NWORDS);
        for (int w = 0; w < 16; ++w) {
            const int tc = part * 16 + w;
            unsigned int m0 = 0, m1 = 0, m2 = 0, m3 = 0;
#pragma unroll
            for (int i = 0; i < 16; ++i) {
                float4 v = spb[i * NWORDS + tc];
                m0 |= (v.x >= 0.5f) ? (1u << i) : 0u;
                m1 |= (v.y >= 0.5f) ? (1u << i) : 0u;
                m2 |= (v.z >= 0.5f) ? (1u << i) : 0u;
                m3 |= (v.w >= 0.5f) ? (1u << i) : 0u;
            }
            mlds[bb][tc] = (unsigned long long)m0 | ((unsigned long long)m1 << 16) |
                           ((unsigned long long)m2 << 32) | ((unsigned long long)m3 << 48);
        }
    }
    __syncthreads();
    double c = 0.0, v = 0.0;
    const int b = blockIdx.x * NB + bb;
    float* outp = out + (size_t)b * T_STEPS;
    const int grp_sh = tid & 48;
    const bool writer = (o == 0);
    for (int tg = 0; tg < NWORDS; ++tg) {
        const unsigned long long mw = mlds[bb][tg];
#pragma unroll
        for (int j = 0; j < 4; ++j) {
            const unsigned int m = (unsigned int)(mw >> (16 * j)) & 0xFFFFu;
            const double z = (ztab[0][m & 15][o] + ztab[1][(m >> 4) & 15][o]) +
                             (ztab[2][(m >> 8) & 15][o] + ztab[3][(m >> 12) & 15][o]);
            c = fma(c, 0.75, z);
            v = fma(v, 0.97, c);
            const bool s = (v >= 1.25);
            const unsigned long long bal = __ballot(s);
            v = s ? 0.0 : v;
            if (writer) outp[tg * 4 + j] = outtab[(int)__popcll((bal >> grp_sh) & 0xFFFFull)];
        }
    }
}

extern "C" void kernel_launch(void* const* d_in, const int* in_sizes, int n_in,
                              void* d_out, int out_size, void* d_ws, size_t ws_size,
                              hipStream_t stream) {
    const float* spike = (const float*)d_in[0];
    const float* W     = (const float*)d_in[1];
    float* out         = (float*)d_out;

    const int B = in_sizes[0] / (16 * T_STEPS);  // 2048

    const size_t mask_bytes = (size_t)B * NWORDS * sizeof(unsigned long long);  // 4 MiB
    const size_t tab_bytes  = 2 * 256 * 16 * sizeof(double);                    // 64 KiB

    if (ws_size >= mask_bytes + tab_bytes) {
        unsigned long long* masks = (unsigned long long*)d_ws;
        double* tab = (double*)((char*)d_ws + mask_bytes);
        // Grid B+1: blocks 0..B-1 build masks, block B builds the byte table.
        k_maskify<<<B + 1, 256, 0, stream>>>(spike, masks, W, tab, B);
        k_scan<<<B / NB, SCAN_BLOCK, 0, stream>>>(tab, masks, out);
    } else {
        k_scan_fb<<<B / NB, SCAN_BLOCK, 0, stream>>>(W, spike, out);
    }
}